// Round 4
// baseline (89.085 us; speedup 1.0000x reference)
//
#include <hip/hip_runtime.h>
#include <hip/hip_bf16.h>

// out[b,s,c] = x[b,s,:] @ W, W[r][c] = kernel[(r%512)*4096 + c]
// xr[m][r'] = sum_{i<8} x[m][r'+512i]  (M=8192, K'=512)
// INT8 GEMM: xq = clamp(round(xr*8), -127,127) i8; B = kernel as i8 (exact,
// values in {-1,0,1}). out = (i32 acc) * 0.125f.
// Round 4 fix: btq transpose pack was index-swapped (packed along c instead
// of r'). Now packs tile[q*4+j][cl] -> btq[c][r'] correctly.

#define M_TOT   8192
#define N_TOT   4096
#define K_RED   512
#define K_FULL  4096
#define NSTEP   8           // K_RED / 64

typedef __attribute__((ext_vector_type(4))) int   i32x4;
typedef __attribute__((ext_vector_type(4))) float f32x4;

// ---------------------------------------------------------------------------
// Prep: blocks [0,4096): xq[m][r'] = i8(clamp(round(8 * sum_{i<8} x[m][r'+512i])))
//       blocks [4096,4608): btq[c][r'] = i8(kernel[r'*4096 + c])  (transpose)
// ---------------------------------------------------------------------------
__global__ __launch_bounds__(256) void prep(const float* __restrict__ x,
                                            const int* __restrict__ kin,
                                            char* __restrict__ xq,
                                            char* __restrict__ btq) {
    __shared__ char tile[64][68];
    if (blockIdx.x < 4096) {
        const int row = blockIdx.x * 2 + (threadIdx.x >> 7);
        const int t2  = threadIdx.x & 127;
        const float* xp = x + (size_t)row * K_FULL + t2 * 4;
        float a0 = 0.f, a1 = 0.f, a2 = 0.f, a3 = 0.f;
#pragma unroll
        for (int i = 0; i < 8; ++i) {
            float4 v = *reinterpret_cast<const float4*>(xp + (size_t)i * K_RED);
            a0 += v.x; a1 += v.y; a2 += v.z; a3 += v.w;
        }
        int q0 = (int)rintf(a0 * 8.f), q1 = (int)rintf(a1 * 8.f);
        int q2 = (int)rintf(a2 * 8.f), q3 = (int)rintf(a3 * 8.f);
        q0 = min(127, max(-127, q0)); q1 = min(127, max(-127, q1));
        q2 = min(127, max(-127, q2)); q3 = min(127, max(-127, q3));
        int packed = (q0 & 0xFF) | ((q1 & 0xFF) << 8) | ((q2 & 0xFF) << 16)
                   | ((q3 & 0xFF) << 24);
        *reinterpret_cast<int*>(xq + (size_t)row * K_RED + t2 * 4) = packed;
    } else {
        const int b  = blockIdx.x - 4096;        // 0..511
        const int c0 = (b & 63) * 64;
        const int r0 = (b >> 6) * 64;
        const int tx = threadIdx.x & 63;
        const int ty = threadIdx.x >> 6;         // 0..3
#pragma unroll
        for (int rr = 0; rr < 64; rr += 4) {
            int r = r0 + rr + ty;
            tile[rr + ty][tx] = (char)kin[(size_t)r * N_TOT + c0 + tx];
        }
        __syncthreads();
        const int q  = tx & 15;                  // r'-quad index (r' = q*4+j)
        const int ch = tx >> 4;                  // 0..3
#pragma unroll
        for (int i = 0; i < 4; ++i) {
            const int cl = i * 16 + ty * 4 + ch; // column offset 0..63
            // pack 4 consecutive r' values at fixed column cl  (THE FIX)
            int p = (tile[q * 4 + 0][cl] & 0xFF)
                  | ((tile[q * 4 + 1][cl] & 0xFF) << 8)
                  | ((tile[q * 4 + 2][cl] & 0xFF) << 16)
                  | ((tile[q * 4 + 3][cl] & 0xFF) << 24);
            *reinterpret_cast<int*>(btq + (size_t)(c0 + cl) * K_RED + r0 + q * 4) = p;
        }
    }
}

// ---------------------------------------------------------------------------
// GEMM: C[8192][4096] f32 = (xq i8 @ btq^T i8) * 0.125
// 256x256 tile, 512 thr = 8 waves (2Mx4N), BK=64, 3 LDS buffers x 32KB = 96KB.
// LDS layout per tile: [kgroup g 0..3][row 0..255][16B]  (conflict-balanced,
// linear for global_load_lds; per-lane global source supplies (g,row) slice).
// ---------------------------------------------------------------------------
__global__ __launch_bounds__(512, 2) void gemm_i8(const char* __restrict__ A,
                                                  const char* __restrict__ Bt,
                                                  float* __restrict__ C) {
    __shared__ char smem[3 * 32768];

    const int tid  = threadIdx.x;
    const int lane = tid & 63;
    const int w    = tid >> 6;        // 0..7
    const int wr   = w >> 2;          // 0..1  (M half)
    const int wc   = w & 3;           // 0..3  (N quarter)
    const int l15  = lane & 15;
    const int lhi  = lane >> 4;       // 0..3  (k-group)

    // XCD-aware bijective swizzle (512 blocks, 512 % 8 == 0)
    const int wg  = blockIdx.x;
    const int swz = (wg & 7) * 64 + (wg >> 3);
    const int m0  = (swz >> 4) * 256;    // 32 m-blocks
    const int n0  = (swz & 15) * 256;    // 16 n-blocks

    // Stage one BK=64 slice: A-tile 16KB + B-tile 16KB into buffer `buf`.
    auto stage = [&](int buf, int t) {
        const int sb = buf * 32768;
#pragma unroll
        for (int it = 0; it < 2; ++it) {
            const int o   = (it * 512 + tid) * 16;   // byte in 16KB tile
            const int g   = o >> 12;                 // k-group 0..3
            const int row = (o & 4095) >> 4;         // 0..255
            const char* ga = A  + (size_t)(m0 + row) * K_RED + t * 64 + g * 16;
            const char* gb = Bt + (size_t)(n0 + row) * K_RED + t * 64 + g * 16;
            __builtin_amdgcn_global_load_lds(
                (__attribute__((address_space(1))) void*)ga,
                (__attribute__((address_space(3))) void*)(smem + sb + o), 16, 0, 0);
            __builtin_amdgcn_global_load_lds(
                (__attribute__((address_space(1))) void*)gb,
                (__attribute__((address_space(3))) void*)(smem + sb + 16384 + o), 16, 0, 0);
        }
    };

    int offA[8], offB[4];
#pragma unroll
    for (int mi = 0; mi < 8; ++mi)
        offA[mi] = (lhi << 12) + ((wr * 128 + mi * 16 + l15) << 4);
#pragma unroll
    for (int ni = 0; ni < 4; ++ni)
        offB[ni] = 16384 + (lhi << 12) + ((wc * 64 + ni * 16 + l15) << 4);

    i32x4 acc[8][4] = {};

    // Prologue: stages 0,1 in flight; retire 0, keep 1 flying.
    stage(0, 0);
    stage(1, 1);
    asm volatile("s_waitcnt vmcnt(4)" ::: "memory");
    __builtin_amdgcn_s_barrier();
    asm volatile("" ::: "memory");

    int cur = 0;
    for (int t = 0; t < NSTEP; ++t) {
        if (t <= NSTEP - 3) {
            int nn = cur + 2; if (nn >= 3) nn -= 3;
            stage(nn, t + 2);
        }
        asm volatile("" ::: "memory");
        const int sb = cur * 32768;
        i32x4 af[8], bfr[4];
#pragma unroll
        for (int mi = 0; mi < 8; ++mi)
            af[mi] = *reinterpret_cast<const i32x4*>(smem + sb + offA[mi]);
#pragma unroll
        for (int ni = 0; ni < 4; ++ni)
            bfr[ni] = *reinterpret_cast<const i32x4*>(smem + sb + offB[ni]);
        __builtin_amdgcn_s_setprio(1);
#pragma unroll
        for (int mi = 0; mi < 8; ++mi)
#pragma unroll
            for (int ni = 0; ni < 4; ++ni)
                acc[mi][ni] = __builtin_amdgcn_mfma_i32_16x16x64_i8(
                    af[mi], bfr[ni], acc[mi][ni], 0, 0, 0);
        __builtin_amdgcn_s_setprio(0);
        asm volatile("" ::: "memory");
        if (t <= NSTEP - 3)       asm volatile("s_waitcnt vmcnt(4)" ::: "memory");
        else if (t == NSTEP - 2)  asm volatile("s_waitcnt vmcnt(0)" ::: "memory");
        if (t <= NSTEP - 2) {
            __builtin_amdgcn_s_barrier();
            asm volatile("" ::: "memory");
        }
        cur += 1; if (cur == 3) cur = 0;
    }

    // Epilogue: C/D layout col = lane&15, row = (lane>>4)*4 + reg; scale 1/8.
#pragma unroll
    for (int mi = 0; mi < 8; ++mi) {
#pragma unroll
        for (int ni = 0; ni < 4; ++ni) {
            const int    col = n0 + wc * 64 + ni * 16 + l15;
            const size_t rb  = m0 + wr * 128 + mi * 16 + lhi * 4;
#pragma unroll
            for (int r = 0; r < 4; ++r) {
                float v = (float)acc[mi][ni][r] * 0.125f;
                __builtin_nontemporal_store(v, &C[(rb + r) * N_TOT + col]);
            }
        }
    }
}

// ---------------------------------------------------------------------------
extern "C" void kernel_launch(void* const* d_in, const int* in_sizes, int n_in,
                              void* d_out, int out_size, void* d_ws, size_t ws_size,
                              hipStream_t stream) {
    const float* x   = (const float*)d_in[0];       // [2,4096,4096] f32
    const int*   kin = (const int*)d_in[1];         // [2097152] int32 in {-1,0,1}
    float*       out = (float*)d_out;               // [2,4096,4096] f32

    char* xq  = (char*)d_ws;                                    // 4 MB
    char* btq = (char*)d_ws + (size_t)M_TOT * K_RED;            // 2 MB

    prep<<<dim3(4096 + 512), 256, 0, stream>>>(x, kin, xq, btq);
    gemm_i8<<<dim3((M_TOT / 256) * (N_TOT / 256)), 512, 0, stream>>>(xq, btq, out);
}

// Round 5
// 77.215 us; speedup vs baseline: 1.1537x; 1.1537x over previous
//
#include <hip/hip_runtime.h>
#include <hip/hip_bf16.h>

// out[b,s,c] = x[b,s,:] @ W, W[r][c] = kernel[(r%512)*4096 + c]
// xr[m][r'] = sum_{i<8} x[m][r'+512i]  (M=8192, K'=512)
// INT8 GEMM: xq = clamp(round(xr*8),-127,127); btq = kernel^T as i8 (exact).
// out = i32 acc * 0.125f.
// Round 5: revert nontemporal stores; LDS-transposed epilogue -> dwordx4
// contiguous C stores (16B/lane, dense 256B segments).

#define M_TOT   8192
#define N_TOT   4096
#define K_RED   512
#define K_FULL  4096
#define NSTEP   8           // K_RED / 64

typedef __attribute__((ext_vector_type(4))) int   i32x4;
typedef __attribute__((ext_vector_type(4))) float f32x4;

// ---------------------------------------------------------------------------
// Prep: blocks [0,4096): xq[m][r'] = i8(clamp(round(8*sum_{i<8} x[m][r'+512i])))
//       blocks [4096,4608): btq[c][r'] = i8(kernel[r'*4096 + c])  (transpose)
// ---------------------------------------------------------------------------
__global__ __launch_bounds__(256) void prep(const float* __restrict__ x,
                                            const int* __restrict__ kin,
                                            char* __restrict__ xq,
                                            char* __restrict__ btq) {
    __shared__ char tile[64][68];
    if (blockIdx.x < 4096) {
        const int row = blockIdx.x * 2 + (threadIdx.x >> 7);
        const int t2  = threadIdx.x & 127;
        const float* xp = x + (size_t)row * K_FULL + t2 * 4;
        float a0 = 0.f, a1 = 0.f, a2 = 0.f, a3 = 0.f;
#pragma unroll
        for (int i = 0; i < 8; ++i) {
            float4 v = *reinterpret_cast<const float4*>(xp + (size_t)i * K_RED);
            a0 += v.x; a1 += v.y; a2 += v.z; a3 += v.w;
        }
        int q0 = (int)rintf(a0 * 8.f), q1 = (int)rintf(a1 * 8.f);
        int q2 = (int)rintf(a2 * 8.f), q3 = (int)rintf(a3 * 8.f);
        q0 = min(127, max(-127, q0)); q1 = min(127, max(-127, q1));
        q2 = min(127, max(-127, q2)); q3 = min(127, max(-127, q3));
        int packed = (q0 & 0xFF) | ((q1 & 0xFF) << 8) | ((q2 & 0xFF) << 16)
                   | ((q3 & 0xFF) << 24);
        *reinterpret_cast<int*>(xq + (size_t)row * K_RED + t2 * 4) = packed;
    } else {
        const int b  = blockIdx.x - 4096;        // 0..511
        const int c0 = (b & 63) * 64;
        const int r0 = (b >> 6) * 64;
        const int tx = threadIdx.x & 63;
        const int ty = threadIdx.x >> 6;         // 0..3
#pragma unroll
        for (int rr = 0; rr < 64; rr += 4) {
            int r = r0 + rr + ty;
            tile[rr + ty][tx] = (char)kin[(size_t)r * N_TOT + c0 + tx];
        }
        __syncthreads();
        const int q  = tx & 15;                  // r'-quad index (r' = q*4+j)
        const int ch = tx >> 4;                  // 0..3
#pragma unroll
        for (int i = 0; i < 4; ++i) {
            const int cl = i * 16 + ty * 4 + ch; // column offset 0..63
            int p = (tile[q * 4 + 0][cl] & 0xFF)
                  | ((tile[q * 4 + 1][cl] & 0xFF) << 8)
                  | ((tile[q * 4 + 2][cl] & 0xFF) << 16)
                  | ((tile[q * 4 + 3][cl] & 0xFF) << 24);
            *reinterpret_cast<int*>(btq + (size_t)(c0 + cl) * K_RED + r0 + q * 4) = p;
        }
    }
}

// ---------------------------------------------------------------------------
// GEMM: C[8192][4096] f32 = (xq i8 @ btq^T i8) * 0.125
// 256x256 tile, 512 thr = 8 waves (2Mx4N), BK=64, 3 LDS buffers x 32KB = 96KB.
// ---------------------------------------------------------------------------
__global__ __launch_bounds__(512, 2) void gemm_i8(const char* __restrict__ A,
                                                  const char* __restrict__ Bt,
                                                  float* __restrict__ C) {
    __shared__ char smem[3 * 32768];

    const int tid  = threadIdx.x;
    const int lane = tid & 63;
    const int w    = tid >> 6;        // 0..7
    const int wr   = w >> 2;          // 0..1  (M half)
    const int wc   = w & 3;           // 0..3  (N quarter)
    const int l15  = lane & 15;
    const int lhi  = lane >> 4;       // 0..3  (k-group)

    // XCD-aware bijective swizzle (512 blocks, 512 % 8 == 0)
    const int wg  = blockIdx.x;
    const int swz = (wg & 7) * 64 + (wg >> 3);
    const int m0  = (swz >> 4) * 256;    // 32 m-blocks
    const int n0  = (swz & 15) * 256;    // 16 n-blocks

    auto stage = [&](int buf, int t) {
        const int sb = buf * 32768;
#pragma unroll
        for (int it = 0; it < 2; ++it) {
            const int o   = (it * 512 + tid) * 16;   // byte in 16KB tile
            const int g   = o >> 12;                 // k-group 0..3
            const int row = (o & 4095) >> 4;         // 0..255
            const char* ga = A  + (size_t)(m0 + row) * K_RED + t * 64 + g * 16;
            const char* gb = Bt + (size_t)(n0 + row) * K_RED + t * 64 + g * 16;
            __builtin_amdgcn_global_load_lds(
                (__attribute__((address_space(1))) void*)ga,
                (__attribute__((address_space(3))) void*)(smem + sb + o), 16, 0, 0);
            __builtin_amdgcn_global_load_lds(
                (__attribute__((address_space(1))) void*)gb,
                (__attribute__((address_space(3))) void*)(smem + sb + 16384 + o), 16, 0, 0);
        }
    };

    int offA[8], offB[4];
#pragma unroll
    for (int mi = 0; mi < 8; ++mi)
        offA[mi] = (lhi << 12) + ((wr * 128 + mi * 16 + l15) << 4);
#pragma unroll
    for (int ni = 0; ni < 4; ++ni)
        offB[ni] = 16384 + (lhi << 12) + ((wc * 64 + ni * 16 + l15) << 4);

    i32x4 acc[8][4] = {};

    stage(0, 0);
    stage(1, 1);
    asm volatile("s_waitcnt vmcnt(4)" ::: "memory");
    __builtin_amdgcn_s_barrier();
    asm volatile("" ::: "memory");

    int cur = 0;
    for (int t = 0; t < NSTEP; ++t) {
        if (t <= NSTEP - 3) {
            int nn = cur + 2; if (nn >= 3) nn -= 3;
            stage(nn, t + 2);
        }
        asm volatile("" ::: "memory");
        const int sb = cur * 32768;
        i32x4 af[8], bfr[4];
#pragma unroll
        for (int mi = 0; mi < 8; ++mi)
            af[mi] = *reinterpret_cast<const i32x4*>(smem + sb + offA[mi]);
#pragma unroll
        for (int ni = 0; ni < 4; ++ni)
            bfr[ni] = *reinterpret_cast<const i32x4*>(smem + sb + offB[ni]);
        __builtin_amdgcn_s_setprio(1);
#pragma unroll
        for (int mi = 0; mi < 8; ++mi)
#pragma unroll
            for (int ni = 0; ni < 4; ++ni)
                acc[mi][ni] = __builtin_amdgcn_mfma_i32_16x16x64_i8(
                    af[mi], bfr[ni], acc[mi][ni], 0, 0, 0);
        __builtin_amdgcn_s_setprio(0);
        asm volatile("" ::: "memory");
        if (t <= NSTEP - 3)       asm volatile("s_waitcnt vmcnt(4)" ::: "memory");
        else if (t == NSTEP - 2)  asm volatile("s_waitcnt vmcnt(0)" ::: "memory");
        if (t <= NSTEP - 2) {
            __builtin_amdgcn_s_barrier();
            asm volatile("" ::: "memory");
        }
        cur += 1; if (cur == 3) cur = 0;
    }

    // ---- Epilogue via per-wave LDS transpose -> dwordx4 stores ----
    // Per-wave private 4KB region in buffer 0 (dead since the t==6 barrier;
    // the final K-step reads buffer 1 only -> disjoint, no barrier needed).
    float* ep = reinterpret_cast<float*>(smem + w * 4096);   // [16][64] f32
#pragma unroll
    for (int mi = 0; mi < 8; ++mi) {
        // scatter-write this wave's 16x64 sub-tile (C/D frag: col=l15,
        // row=lhi*4+r within each 16x16 fragment)
#pragma unroll
        for (int ni = 0; ni < 4; ++ni)
#pragma unroll
            for (int r = 0; r < 4; ++r)
                ep[(lhi * 4 + r) * 64 + ni * 16 + l15] =
                    (float)acc[mi][ni][r] * 0.125f;
        __builtin_amdgcn_s_waitcnt(0);  // lgkmcnt(0): writes visible to own reads
        // coalesced read-back + dense dwordx4 stores
#pragma unroll
        for (int j = 0; j < 4; ++j) {
            const int row = j * 4 + lhi;        // 0..15
            const int c4  = l15 * 4;            // 0..60
            f32x4 v = *reinterpret_cast<const f32x4*>(&ep[row * 64 + c4]);
            const size_t gr = (size_t)(m0 + wr * 128 + mi * 16 + row);
            *reinterpret_cast<f32x4*>(&C[gr * N_TOT + n0 + wc * 64 + c4]) = v;
        }
        __builtin_amdgcn_s_waitcnt(0);  // reads done before next mi overwrites
    }
}

// ---------------------------------------------------------------------------
extern "C" void kernel_launch(void* const* d_in, const int* in_sizes, int n_in,
                              void* d_out, int out_size, void* d_ws, size_t ws_size,
                              hipStream_t stream) {
    const float* x   = (const float*)d_in[0];       // [2,4096,4096] f32
    const int*   kin = (const int*)d_in[1];         // [2097152] int32 in {-1,0,1}
    float*       out = (float*)d_out;               // [2,4096,4096] f32

    char* xq  = (char*)d_ws;                                    // 4 MB
    char* btq = (char*)d_ws + (size_t)M_TOT * K_RED;            // 2 MB

    prep<<<dim3(4096 + 512), 256, 0, stream>>>(x, kin, xq, btq);
    gemm_i8<<<dim3((M_TOT / 256) * (N_TOT / 256)), 512, 0, stream>>>(xq, btq, out);
}